// Round 10
// baseline (385.739 us; speedup 1.0000x reference)
//
#include <hip/hip_runtime.h>

#define NN 4096
#define DD 512
#define FF 512
#define HH 4

typedef _Float16 f16;
typedef f16 f16x8 __attribute__((ext_vector_type(8)));
typedef f16 f16x4 __attribute__((ext_vector_type(4)));
typedef float f32x4 __attribute__((ext_vector_type(4)));

#define BM 128
#define BN 64
#define BK 32
#define LDK 40   // padded LDS row stride (f16 elems) for the manual-staging GEMMs

// ---------------- async global->LDS (16 B per lane; LDS dest = uniform base + lane*16) ----------------
typedef __attribute__((address_space(1))) void gvoid;
typedef __attribute__((address_space(3))) void svoid;
__device__ __forceinline__ void glds16(const void* g, void* s) {
    __builtin_amdgcn_global_load_lds((gvoid*)g, (svoid*)s, 16, 0, 0);
}

// ---------------- static device workspace (fully rewritten every call) ----------------
__device__ __attribute__((aligned(16))) f16 g_nodesH[NN * DD];       //  4 MB
__device__ __attribute__((aligned(16))) f16 g_XH[NN * DD];           //  4 MB  edges+labels
__device__ __attribute__((aligned(16))) f16 g_WeTH[FF * DD];         //  0.5 MB  We^T[f][d]
__device__ __attribute__((aligned(16))) f16 g_WTH[HH * FF * DD];     //  2 MB  W^T[h][f][d]
__device__ __attribute__((aligned(16))) f16 g_eH[FF * NN];           //  4 MB  e^T[f][n]
__device__ __attribute__((aligned(16))) f16 g_featsH[HH * FF * NN];  // 16 MB  (feats+e)^T
__device__ __attribute__((aligned(16))) float g_oacc[2 * HH * NN * FF];   // 67 MB (h,ks) partials
__device__ float g_beF[FF];
__device__ float g_bF[HH * FF];
__device__ float g_tu[HH * DD], g_tv[HH * DD], g_bu[HH], g_bv[HH];
__device__ float g_p[HH * NN], g_q[HH * NN], g_M[HH * NN], g_sc[HH * NN];

#define PREP_CONV 16394
#define PREP_TRAN 320
#define PREP_UV   513

// ---------------- fused prep: fp32->f16 staging + weight transposes + u/v projections ----------------
__global__ __launch_bounds__(256) void k_prep(const float* __restrict__ nodes, const float* __restrict__ edges,
                                              const float* __restrict__ labels, const float* __restrict__ We,
                                              const float* __restrict__ W, const float* __restrict__ be,
                                              const float* __restrict__ b, const float* __restrict__ u,
                                              const float* __restrict__ v) {
    __shared__ float lds[64 * 65];
    int bx = blockIdx.x;
    int tid = threadIdx.x;
    if (bx < PREP_CONV) {
        int id = bx * 256 + tid;
        const int NDE = NN * DD;
        if (id < NDE) { g_nodesH[id] = (f16)nodes[id]; return; }
        id -= NDE;
        if (id < NDE) { g_XH[id] = (f16)(edges[id] + labels[id]); return; }
        id -= NDE;
        if (id < FF) { g_beF[id] = be[id]; return; }
        id -= FF;
        if (id < HH * FF) { g_bF[id] = b[id]; return; }
        return;
    }
    if (bx < PREP_CONV + PREP_TRAN) {
        int bid = bx - PREP_CONV;                    // 0..319
        int mi = bid >> 6;                           // 0 = We, 1..4 = W head
        int t64 = bid & 63;
        const float* src = (mi == 0) ? We : (W + (size_t)(mi - 1) * DD * FF);
        f16* dst = (mi == 0) ? g_WeTH : (g_WTH + (size_t)(mi - 1) * FF * DD);
        int ti = t64 >> 3, tj = t64 & 7;
        int r = tid >> 2, cseg = (tid & 3) * 16;
#pragma unroll
        for (int kq = 0; kq < 4; ++kq) {
            f32x4 vv = *(const f32x4*)(src + (size_t)(ti * 64 + r) * 512 + tj * 64 + cseg + kq * 4);
            *(f32x4*)&lds[r * 65 + cseg + kq * 4] = vv;
        }
        __syncthreads();
        int fl = tid >> 2, dseg = (tid & 3) * 16;
        f16x8 o0, o1;
#pragma unroll
        for (int k = 0; k < 8; ++k) o0[k] = (f16)lds[(dseg + k) * 65 + fl];
#pragma unroll
        for (int k = 0; k < 8; ++k) o1[k] = (f16)lds[(dseg + 8 + k) * 65 + fl];
        size_t ob = (size_t)(tj * 64 + fl) * 512 + ti * 64 + dseg;
        *(f16x8*)&dst[ob] = o0;
        *(f16x8*)&dst[ob + 8] = o1;
        return;
    }
    {
        int row = (bx - PREP_CONV - PREP_TRAN) * 4 + (tid >> 6);   // 2052 rows
        int lane = tid & 63;
        float su = 0.f, sv = 0.f;
        if (row < HH * DD) {
            int h = row >> 9, d = row & 511;
            size_t wb = (size_t)h * DD * FF + (size_t)d * FF;
#pragma unroll
            for (int j = 0; j < 8; ++j) {
                int f = lane + 64 * j;
                float wv = W[wb + f];
                su += wv * u[(size_t)h * FF + f];
                sv += wv * v[(size_t)h * FF + f];
            }
        } else if (row < HH * DD + HH) {
            int h = row - HH * DD;
#pragma unroll
            for (int j = 0; j < 8; ++j) {
                int f = lane + 64 * j;
                float bvv = b[(size_t)h * FF + f];
                su += bvv * u[(size_t)h * FF + f];
                sv += bvv * v[(size_t)h * FF + f];
            }
        }
#pragma unroll
        for (int m = 1; m < 64; m <<= 1) {
            su += __shfl_xor(su, m, 64);
            sv += __shfl_xor(sv, m, 64);
        }
        if (lane == 0 && row < HH * DD + HH) {
            if (row < HH * DD) { g_tu[row] = su; g_tv[row] = sv; }
            else { g_bu[row - HH * DD] = su; g_bv[row - HH * DD] = sv; }
        }
    }
}

// ---------------- p[h][n] = nodes[n].t_u[h] + bu[h];  q likewise (exact fp32 score path) ----------------
__global__ __launch_bounds__(256) void k_pq() {
    int row = blockIdx.x * 4 + (threadIdx.x >> 6);    // 4096 blocks -> 16384 rows = H*N
    int lane = threadIdx.x & 63;
    int h = row >> 12, n = row & 4095;
    const f16* nb = g_nodesH + (size_t)n * DD;
    const float* tu = g_tu + h * DD;
    const float* tv = g_tv + h * DD;
    float pa = 0.f, qa = 0.f;
#pragma unroll
    for (int j = 0; j < 8; ++j) {
        int d = lane + 64 * j;
        float nv = (float)nb[d];
        pa += nv * tu[d];
        qa += nv * tv[d];
    }
#pragma unroll
    for (int m = 1; m < 64; m <<= 1) {
        pa += __shfl_xor(pa, m, 64);
        qa += __shfl_xor(qa, m, 64);
    }
    if (lane == 0) {
        g_p[row] = pa + g_bu[h];
        g_q[row] = qa + g_bv[h];
    }
}

// ---------------- GEMM1: eH[f][n] = f16((X @ We)[n][f] + be[f]) ----------------
__global__ __launch_bounds__(256) void k_gemm_e() {
    __shared__ f16 As[BM * LDK];
    __shared__ f16 Bs[BN * LDK];
    int tid = threadIdx.x;
    int n0 = blockIdx.x * BM, f0 = blockIdx.y * BN;
    int lane = tid & 63, wave = tid >> 6, wr = wave >> 1, wc = wave & 1;
    int c = lane & 15, g = lane >> 4;
    int arow = tid >> 2, kpart = (tid & 3) * 8;
    f32x4 acc[4][2] = {};
    for (int kk = 0; kk < DD; kk += BK) {
        f16x8 a0 = *(const f16x8*)(g_XH + (size_t)(n0 + arow) * DD + kk + kpart);
        f16x8 a1 = *(const f16x8*)(g_XH + (size_t)(n0 + arow + 64) * DD + kk + kpart);
        f16x8 b0 = *(const f16x8*)(g_WeTH + (size_t)(f0 + arow) * DD + kk + kpart);
        __syncthreads();
        *(f16x8*)&As[arow * LDK + kpart] = a0;
        *(f16x8*)&As[(arow + 64) * LDK + kpart] = a1;
        *(f16x8*)&Bs[arow * LDK + kpart] = b0;
        __syncthreads();
        f16x8 af[4], bfr[2];
#pragma unroll
        for (int i = 0; i < 4; ++i) af[i] = *(const f16x8*)&As[(wr * 64 + i * 16 + c) * LDK + g * 8];
#pragma unroll
        for (int jj = 0; jj < 2; ++jj) bfr[jj] = *(const f16x8*)&Bs[(wc * 32 + jj * 16 + c) * LDK + g * 8];
#pragma unroll
        for (int i = 0; i < 4; ++i)
#pragma unroll
            for (int jj = 0; jj < 2; ++jj)
                acc[i][jj] = __builtin_amdgcn_mfma_f32_16x16x32_f16(af[i], bfr[jj], acc[i][jj], 0, 0, 0);
    }
#pragma unroll
    for (int jj = 0; jj < 2; ++jj) {
        int f = f0 + wc * 32 + jj * 16 + c;
        float bv = g_beF[f];
#pragma unroll
        for (int i = 0; i < 4; ++i) {
            int r0 = n0 + wr * 64 + i * 16 + g * 4;
            f16x4 ov;
#pragma unroll
            for (int rr = 0; rr < 4; ++rr) ov[rr] = (f16)(acc[i][jj][rr] + bv);
            *(f16x4*)(g_eH + (size_t)f * NN + r0) = ov;
        }
    }
}

// ---------------- GEMM2: featsH[h][f][n] = f16((nodes @ W_h)[n][f] + b_h[f] + e[n][f]) ----------------
__global__ __launch_bounds__(256) void k_gemm_feats() {
    __shared__ f16 As[BM * LDK];
    __shared__ f16 Bs[BN * LDK];
    int tid = threadIdx.x;
    int h = blockIdx.z;
    int n0 = blockIdx.x * BM, f0 = blockIdx.y * BN;
    int lane = tid & 63, wave = tid >> 6, wr = wave >> 1, wc = wave & 1;
    int c = lane & 15, g = lane >> 4;
    int arow = tid >> 2, kpart = (tid & 3) * 8;
    const f16* BT = g_WTH + (size_t)h * DD * FF;
    f32x4 acc[4][2] = {};
    for (int kk = 0; kk < DD; kk += BK) {
        f16x8 a0 = *(const f16x8*)(g_nodesH + (size_t)(n0 + arow) * DD + kk + kpart);
        f16x8 a1 = *(const f16x8*)(g_nodesH + (size_t)(n0 + arow + 64) * DD + kk + kpart);
        f16x8 b0 = *(const f16x8*)(BT + (size_t)(f0 + arow) * DD + kk + kpart);
        __syncthreads();
        *(f16x8*)&As[arow * LDK + kpart] = a0;
        *(f16x8*)&As[(arow + 64) * LDK + kpart] = a1;
        *(f16x8*)&Bs[arow * LDK + kpart] = b0;
        __syncthreads();
        f16x8 af[4], bfr[2];
#pragma unroll
        for (int i = 0; i < 4; ++i) af[i] = *(const f16x8*)&As[(wr * 64 + i * 16 + c) * LDK + g * 8];
#pragma unroll
        for (int jj = 0; jj < 2; ++jj) bfr[jj] = *(const f16x8*)&Bs[(wc * 32 + jj * 16 + c) * LDK + g * 8];
#pragma unroll
        for (int i = 0; i < 4; ++i)
#pragma unroll
            for (int jj = 0; jj < 2; ++jj)
                acc[i][jj] = __builtin_amdgcn_mfma_f32_16x16x32_f16(af[i], bfr[jj], acc[i][jj], 0, 0, 0);
    }
#pragma unroll
    for (int jj = 0; jj < 2; ++jj) {
        int f = f0 + wc * 32 + jj * 16 + c;
        float bv = g_bF[h * FF + f];
#pragma unroll
        for (int i = 0; i < 4; ++i) {
            int r0 = n0 + wr * 64 + i * 16 + g * 4;
            f16x4 e4 = *(const f16x4*)(g_eH + (size_t)f * NN + r0);
            f16x4 ov;
#pragma unroll
            for (int rr = 0; rr < 4; ++rr)
                ov[rr] = (f16)(acc[i][jj][rr] + bv + (float)e4[rr]);
            *(f16x4*)(g_featsH + ((size_t)h * FF + f) * NN + r0) = ov;
        }
    }
}

// ---------------- softmax stats: closed-form M (lrelu monotone), single Z pass ----------------
__global__ __launch_bounds__(256) void k_msz() {
    __shared__ float qsh[NN];
    __shared__ float red[256];
    int h = blockIdx.y;
    int tid = threadIdx.x;
    float lmax = -1e30f, lmin = 1e30f;
    for (int i = tid; i < NN; i += 256) {
        float qv = g_q[h * NN + i];
        qsh[i] = qv;
        lmax = fmaxf(lmax, qv);
        lmin = fminf(lmin, qv);
    }
    red[tid] = lmax;
    __syncthreads();
    for (int s = 128; s > 0; s >>= 1) {
        if (tid < s) red[tid] = fmaxf(red[tid], red[tid + s]);
        __syncthreads();
    }
    float qmax = red[0];
    __syncthreads();
    red[tid] = lmin;
    __syncthreads();
    for (int s = 128; s > 0; s >>= 1) {
        if (tid < s) red[tid] = fminf(red[tid], red[tid + s]);
        __syncthreads();
    }
    float qmin = red[0];
    __syncthreads();
    int nl = tid & 15, chunk = tid >> 4;             // 16 rows/block, 16 k-chunks of 256
    int n = blockIdx.x * 16 + nl;
    float pv = g_p[h * NN + n];
    float se = pv * (pv >= 0.f ? qmax : qmin);
    float M = fmaxf(se, 0.3f * se);
    float z = 0.f;
    int base = chunk * 256;
    for (int i = 0; i < 64; ++i) {
        f32x4 qv = *(const f32x4*)&qsh[base + i * 4];
#pragma unroll
        for (int k = 0; k < 4; ++k) {
            float s = pv * qv[k];
            s = fmaxf(s, 0.3f * s);
            z += __expf(s - M);
        }
    }
    red[chunk * 16 + nl] = z;
    __syncthreads();
    if (chunk == 0) {
        float Z = 0.f;
#pragma unroll
        for (int t = 0; t < 16; ++t) Z += red[t * 16 + nl];
        g_M[h * NN + n] = M;
        g_sc[h * NN + n] = 0.25f / Z;
    }
}

// ---------------- GEMM3 v6: 32n x 512f tile, 1x exp redundancy, grid 1024 (1-D),
//                  XCD-aligned: grp = bx&7 (= h*2+ks) so all n-blocks of a group share an XCD's L2.
//                  4 blocks/CU, 16 waves/CU. oacc[grp][n][f] = sum_m w_h[n][m]*featsH[h][f][m] ----------------
__global__ __launch_bounds__(256, 4) void k_gemm_out() {
    __shared__ f16 As[32 * 32];         //  2 KB  [n][k]
    __shared__ f16 Bs[512 * 32];        // 32 KB  [f][k]; wave w owns f rows [w*128, w*128+128)
    int bx = blockIdx.x;
    int grp = bx & 7;                            // h*2+ks — XCD-resident group
    int h = grp >> 1, ks = grp & 1;
    int n0 = (bx >> 3) * 32;
    int tid = threadIdx.x;
    int lane = tid & 63, wave = tid >> 6;        // 4 waves; wave = f-128-slice
    int c = lane & 15, g = lane >> 4;
    int wn = tid >> 3, kq = (tid & 7) * 4;       // weight-gen: row wn (0..31), 4 k's per thread
    float pv = g_p[h * NN + n0 + wn];
    float mv = g_M[h * NN + n0 + wn];
    float sv = g_sc[h * NN + n0 + wn];
    const float* qh = g_q + h * NN + ks * 2048;
    const f16* Bgl = g_featsH + (size_t)h * FF * NN + (size_t)ks * 2048;
    int brow = lane >> 2;                        // glds: lane's row within a 16-row group
    int bkof = (lane & 3) * 8;                   //       lane's k offset (f16 elems)
    f32x4 acc[2][8] = {};
    for (int kk = 0; kk < 2048; kk += BK) {
        // this iter's 4 attention weights, generated in registers (pre-barrier)
        f32x4 q0 = *(const f32x4*)(qh + kk + kq);
        f16x4 w;
#pragma unroll
        for (int k = 0; k < 4; ++k) {
            float s = pv * q0[k];
            s = fmaxf(s, 0.3f * s);
            w[k] = (f16)(__expf(s - mv) * sv);
        }
        __syncthreads();   // previous iteration's LDS readers done
        *(f16x4*)&As[wn * 32 + kq] = w;          // 256 thr x 8 B = full 2 KB A tile, linear
        // B: wave stages its own 128 f-rows: 8 glds16 of 16 rows each
#pragma unroll
        for (int j = 0; j < 8; ++j) {
            int frow = wave * 128 + j * 16;
            glds16(Bgl + (size_t)(frow + brow) * NN + kk + bkof, &Bs[frow * 32]);
        }
        __syncthreads();   // drain -> tiles ready
        f16x8 af[2], bfr[8];
#pragma unroll
        for (int i = 0; i < 2; ++i) af[i] = *(const f16x8*)&As[(i * 16 + c) * 32 + g * 8];
#pragma unroll
        for (int jj = 0; jj < 8; ++jj) bfr[jj] = *(const f16x8*)&Bs[(wave * 128 + jj * 16 + c) * 32 + g * 8];
#pragma unroll
        for (int i = 0; i < 2; ++i)
#pragma unroll
            for (int jj = 0; jj < 8; ++jj)
                acc[i][jj] = __builtin_amdgcn_mfma_f32_16x16x32_f16(af[i], bfr[jj], acc[i][jj], 0, 0, 0);
    }
    float* O = g_oacc + (size_t)grp * NN * FF;
#pragma unroll
    for (int jj = 0; jj < 8; ++jj) {
        int f = wave * 128 + jj * 16 + c;
#pragma unroll
        for (int i = 0; i < 2; ++i) {
            int r0 = n0 + i * 16 + g * 4;
#pragma unroll
            for (int rr = 0; rr < 4; ++rr)
                O[(size_t)(r0 + rr) * FF + f] = acc[i][jj][rr];
        }
    }
}

// ---------------- final: out = relu(sum over 8 (h,ks) slabs) (fp32 out) ----------------
__global__ void k_reduce(float* __restrict__ out) {
    size_t i = ((size_t)blockIdx.x * 256 + threadIdx.x) * 4;   // 2048 blocks
    const size_t NF = (size_t)NN * FF;
    f32x4 s = *(const f32x4*)(g_oacc + i);
#pragma unroll
    for (int sl = 1; sl < 8; ++sl)
        s = s + *(const f32x4*)(g_oacc + sl * NF + i);
    f32x4 o;
#pragma unroll
    for (int rr = 0; rr < 4; ++rr) o[rr] = fmaxf(s[rr], 0.f);
    *(f32x4*)(out + i) = o;
}

extern "C" void kernel_launch(void* const* d_in, const int* in_sizes, int n_in,
                              void* d_out, int out_size, void* d_ws, size_t ws_size,
                              hipStream_t stream) {
    (void)in_sizes; (void)n_in; (void)out_size; (void)d_ws; (void)ws_size;
    const float* nodes  = (const float*)d_in[0];
    const float* edges  = (const float*)d_in[1];
    const float* labels = (const float*)d_in[2];
    const float* We     = (const float*)d_in[3];
    const float* be     = (const float*)d_in[4];
    const float* W      = (const float*)d_in[5];
    const float* b      = (const float*)d_in[6];
    const float* u      = (const float*)d_in[7];
    const float* v      = (const float*)d_in[8];

    k_prep<<<PREP_CONV + PREP_TRAN + PREP_UV, 256, 0, stream>>>(nodes, edges, labels, We, W, be, b, u, v);
    k_pq<<<4096, 256, 0, stream>>>();
    k_gemm_e<<<dim3(32, 8), 256, 0, stream>>>();
    k_gemm_feats<<<dim3(32, 8, 4), 256, 0, stream>>>();
    k_msz<<<dim3(256, 4), 256, 0, stream>>>();
    k_gemm_out<<<1024, 256, 0, stream>>>();
    k_reduce<<<2048, 256, 0, stream>>>((float*)d_out);
}

// Round 11
// 279.486 us; speedup vs baseline: 1.3802x; 1.3802x over previous
//
#include <hip/hip_runtime.h>

#define NN 4096
#define DD 512
#define FF 512
#define HH 4

typedef _Float16 f16;
typedef f16 f16x8 __attribute__((ext_vector_type(8)));
typedef f16 f16x4 __attribute__((ext_vector_type(4)));
typedef float f32x4 __attribute__((ext_vector_type(4)));

#define BM 128
#define BN 64
#define BK 32
#define LDK 40   // padded LDS row stride (f16 elems) for the manual-staging GEMMs

// ---------------- async global->LDS (16 B per lane; LDS dest = uniform base + lane*16) ----------------
typedef __attribute__((address_space(1))) void gvoid;
typedef __attribute__((address_space(3))) void svoid;
__device__ __forceinline__ void glds16(const void* g, void* s) {
    __builtin_amdgcn_global_load_lds((gvoid*)g, (svoid*)s, 16, 0, 0);
}

// ---------------- static device workspace (fully rewritten every call) ----------------
__device__ __attribute__((aligned(16))) f16 g_nodesH[NN * DD];       //  4 MB
__device__ __attribute__((aligned(16))) f16 g_XH[NN * DD];           //  4 MB  edges+labels
__device__ __attribute__((aligned(16))) f16 g_WeTH[FF * DD];         //  0.5 MB  We^T[f][d]
__device__ __attribute__((aligned(16))) f16 g_WTH[HH * FF * DD];     //  2 MB  W^T[h][f][d]
__device__ __attribute__((aligned(16))) f16 g_eH[FF * NN];           //  4 MB  e^T[f][n]
__device__ __attribute__((aligned(16))) f16 g_featsH[HH * FF * NN];  // 16 MB  (feats+e)^T
__device__ __attribute__((aligned(16))) float g_oacc[2 * HH * NN * FF];   // 67 MB (h,ks) partials
__device__ float g_beF[FF];
__device__ float g_bF[HH * FF];
__device__ float g_tu[HH * DD], g_tv[HH * DD], g_bu[HH], g_bv[HH];
__device__ float g_p[HH * NN], g_q[HH * NN], g_M[HH * NN], g_sc[HH * NN];

#define PREP_CONV 16394
#define PREP_TRAN 320
#define PREP_UV   513

// ---------------- fused prep: fp32->f16 staging + weight transposes + u/v projections ----------------
__global__ __launch_bounds__(256) void k_prep(const float* __restrict__ nodes, const float* __restrict__ edges,
                                              const float* __restrict__ labels, const float* __restrict__ We,
                                              const float* __restrict__ W, const float* __restrict__ be,
                                              const float* __restrict__ b, const float* __restrict__ u,
                                              const float* __restrict__ v) {
    __shared__ float lds[64 * 65];
    int bx = blockIdx.x;
    int tid = threadIdx.x;
    if (bx < PREP_CONV) {
        int id = bx * 256 + tid;
        const int NDE = NN * DD;
        if (id < NDE) { g_nodesH[id] = (f16)nodes[id]; return; }
        id -= NDE;
        if (id < NDE) { g_XH[id] = (f16)(edges[id] + labels[id]); return; }
        id -= NDE;
        if (id < FF) { g_beF[id] = be[id]; return; }
        id -= FF;
        if (id < HH * FF) { g_bF[id] = b[id]; return; }
        return;
    }
    if (bx < PREP_CONV + PREP_TRAN) {
        int bid = bx - PREP_CONV;                    // 0..319
        int mi = bid >> 6;                           // 0 = We, 1..4 = W head
        int t64 = bid & 63;
        const float* src = (mi == 0) ? We : (W + (size_t)(mi - 1) * DD * FF);
        f16* dst = (mi == 0) ? g_WeTH : (g_WTH + (size_t)(mi - 1) * FF * DD);
        int ti = t64 >> 3, tj = t64 & 7;
        int r = tid >> 2, cseg = (tid & 3) * 16;
#pragma unroll
        for (int kq = 0; kq < 4; ++kq) {
            f32x4 vv = *(const f32x4*)(src + (size_t)(ti * 64 + r) * 512 + tj * 64 + cseg + kq * 4);
            *(f32x4*)&lds[r * 65 + cseg + kq * 4] = vv;
        }
        __syncthreads();
        int fl = tid >> 2, dseg = (tid & 3) * 16;
        f16x8 o0, o1;
#pragma unroll
        for (int k = 0; k < 8; ++k) o0[k] = (f16)lds[(dseg + k) * 65 + fl];
#pragma unroll
        for (int k = 0; k < 8; ++k) o1[k] = (f16)lds[(dseg + 8 + k) * 65 + fl];
        size_t ob = (size_t)(tj * 64 + fl) * 512 + ti * 64 + dseg;
        *(f16x8*)&dst[ob] = o0;
        *(f16x8*)&dst[ob + 8] = o1;
        return;
    }
    {
        int row = (bx - PREP_CONV - PREP_TRAN) * 4 + (tid >> 6);   // 2052 rows
        int lane = tid & 63;
        float su = 0.f, sv = 0.f;
        if (row < HH * DD) {
            int h = row >> 9, d = row & 511;
            size_t wb = (size_t)h * DD * FF + (size_t)d * FF;
#pragma unroll
            for (int j = 0; j < 8; ++j) {
                int f = lane + 64 * j;
                float wv = W[wb + f];
                su += wv * u[(size_t)h * FF + f];
                sv += wv * v[(size_t)h * FF + f];
            }
        } else if (row < HH * DD + HH) {
            int h = row - HH * DD;
#pragma unroll
            for (int j = 0; j < 8; ++j) {
                int f = lane + 64 * j;
                float bvv = b[(size_t)h * FF + f];
                su += bvv * u[(size_t)h * FF + f];
                sv += bvv * v[(size_t)h * FF + f];
            }
        }
#pragma unroll
        for (int m = 1; m < 64; m <<= 1) {
            su += __shfl_xor(su, m, 64);
            sv += __shfl_xor(sv, m, 64);
        }
        if (lane == 0 && row < HH * DD + HH) {
            if (row < HH * DD) { g_tu[row] = su; g_tv[row] = sv; }
            else { g_bu[row - HH * DD] = su; g_bv[row - HH * DD] = sv; }
        }
    }
}

// ---------------- p[h][n] = nodes[n].t_u[h] + bu[h];  q likewise (exact fp32 score path) ----------------
__global__ __launch_bounds__(256) void k_pq() {
    int row = blockIdx.x * 4 + (threadIdx.x >> 6);    // 4096 blocks -> 16384 rows = H*N
    int lane = threadIdx.x & 63;
    int h = row >> 12, n = row & 4095;
    const f16* nb = g_nodesH + (size_t)n * DD;
    const float* tu = g_tu + h * DD;
    const float* tv = g_tv + h * DD;
    float pa = 0.f, qa = 0.f;
#pragma unroll
    for (int j = 0; j < 8; ++j) {
        int d = lane + 64 * j;
        float nv = (float)nb[d];
        pa += nv * tu[d];
        qa += nv * tv[d];
    }
#pragma unroll
    for (int m = 1; m < 64; m <<= 1) {
        pa += __shfl_xor(pa, m, 64);
        qa += __shfl_xor(qa, m, 64);
    }
    if (lane == 0) {
        g_p[row] = pa + g_bu[h];
        g_q[row] = qa + g_bv[h];
    }
}

// ---------------- GEMM1: eH[f][n] = f16((X @ We)[n][f] + be[f]) ----------------
__global__ __launch_bounds__(256) void k_gemm_e() {
    __shared__ f16 As[BM * LDK];
    __shared__ f16 Bs[BN * LDK];
    int tid = threadIdx.x;
    int n0 = blockIdx.x * BM, f0 = blockIdx.y * BN;
    int lane = tid & 63, wave = tid >> 6, wr = wave >> 1, wc = wave & 1;
    int c = lane & 15, g = lane >> 4;
    int arow = tid >> 2, kpart = (tid & 3) * 8;
    f32x4 acc[4][2] = {};
    for (int kk = 0; kk < DD; kk += BK) {
        f16x8 a0 = *(const f16x8*)(g_XH + (size_t)(n0 + arow) * DD + kk + kpart);
        f16x8 a1 = *(const f16x8*)(g_XH + (size_t)(n0 + arow + 64) * DD + kk + kpart);
        f16x8 b0 = *(const f16x8*)(g_WeTH + (size_t)(f0 + arow) * DD + kk + kpart);
        __syncthreads();
        *(f16x8*)&As[arow * LDK + kpart] = a0;
        *(f16x8*)&As[(arow + 64) * LDK + kpart] = a1;
        *(f16x8*)&Bs[arow * LDK + kpart] = b0;
        __syncthreads();
        f16x8 af[4], bfr[2];
#pragma unroll
        for (int i = 0; i < 4; ++i) af[i] = *(const f16x8*)&As[(wr * 64 + i * 16 + c) * LDK + g * 8];
#pragma unroll
        for (int jj = 0; jj < 2; ++jj) bfr[jj] = *(const f16x8*)&Bs[(wc * 32 + jj * 16 + c) * LDK + g * 8];
#pragma unroll
        for (int i = 0; i < 4; ++i)
#pragma unroll
            for (int jj = 0; jj < 2; ++jj)
                acc[i][jj] = __builtin_amdgcn_mfma_f32_16x16x32_f16(af[i], bfr[jj], acc[i][jj], 0, 0, 0);
    }
#pragma unroll
    for (int jj = 0; jj < 2; ++jj) {
        int f = f0 + wc * 32 + jj * 16 + c;
        float bv = g_beF[f];
#pragma unroll
        for (int i = 0; i < 4; ++i) {
            int r0 = n0 + wr * 64 + i * 16 + g * 4;
            f16x4 ov;
#pragma unroll
            for (int rr = 0; rr < 4; ++rr) ov[rr] = (f16)(acc[i][jj][rr] + bv);
            *(f16x4*)(g_eH + (size_t)f * NN + r0) = ov;
        }
    }
}

// ---------------- GEMM2: featsH[h][f][n] = f16((nodes @ W_h)[n][f] + b_h[f] + e[n][f]) ----------------
__global__ __launch_bounds__(256) void k_gemm_feats() {
    __shared__ f16 As[BM * LDK];
    __shared__ f16 Bs[BN * LDK];
    int tid = threadIdx.x;
    int h = blockIdx.z;
    int n0 = blockIdx.x * BM, f0 = blockIdx.y * BN;
    int lane = tid & 63, wave = tid >> 6, wr = wave >> 1, wc = wave & 1;
    int c = lane & 15, g = lane >> 4;
    int arow = tid >> 2, kpart = (tid & 3) * 8;
    const f16* BT = g_WTH + (size_t)h * DD * FF;
    f32x4 acc[4][2] = {};
    for (int kk = 0; kk < DD; kk += BK) {
        f16x8 a0 = *(const f16x8*)(g_nodesH + (size_t)(n0 + arow) * DD + kk + kpart);
        f16x8 a1 = *(const f16x8*)(g_nodesH + (size_t)(n0 + arow + 64) * DD + kk + kpart);
        f16x8 b0 = *(const f16x8*)(BT + (size_t)(f0 + arow) * DD + kk + kpart);
        __syncthreads();
        *(f16x8*)&As[arow * LDK + kpart] = a0;
        *(f16x8*)&As[(arow + 64) * LDK + kpart] = a1;
        *(f16x8*)&Bs[arow * LDK + kpart] = b0;
        __syncthreads();
        f16x8 af[4], bfr[2];
#pragma unroll
        for (int i = 0; i < 4; ++i) af[i] = *(const f16x8*)&As[(wr * 64 + i * 16 + c) * LDK + g * 8];
#pragma unroll
        for (int jj = 0; jj < 2; ++jj) bfr[jj] = *(const f16x8*)&Bs[(wc * 32 + jj * 16 + c) * LDK + g * 8];
#pragma unroll
        for (int i = 0; i < 4; ++i)
#pragma unroll
            for (int jj = 0; jj < 2; ++jj)
                acc[i][jj] = __builtin_amdgcn_mfma_f32_16x16x32_f16(af[i], bfr[jj], acc[i][jj], 0, 0, 0);
    }
#pragma unroll
    for (int jj = 0; jj < 2; ++jj) {
        int f = f0 + wc * 32 + jj * 16 + c;
        float bv = g_bF[h * FF + f];
#pragma unroll
        for (int i = 0; i < 4; ++i) {
            int r0 = n0 + wr * 64 + i * 16 + g * 4;
            f16x4 e4 = *(const f16x4*)(g_eH + (size_t)f * NN + r0);
            f16x4 ov;
#pragma unroll
            for (int rr = 0; rr < 4; ++rr)
                ov[rr] = (f16)(acc[i][jj][rr] + bv + (float)e4[rr]);
            *(f16x4*)(g_featsH + ((size_t)h * FF + f) * NN + r0) = ov;
        }
    }
}

// ---------------- softmax stats: closed-form M (lrelu monotone), single Z pass ----------------
__global__ __launch_bounds__(256) void k_msz() {
    __shared__ float qsh[NN];
    __shared__ float red[256];
    int h = blockIdx.y;
    int tid = threadIdx.x;
    float lmax = -1e30f, lmin = 1e30f;
    for (int i = tid; i < NN; i += 256) {
        float qv = g_q[h * NN + i];
        qsh[i] = qv;
        lmax = fmaxf(lmax, qv);
        lmin = fminf(lmin, qv);
    }
    red[tid] = lmax;
    __syncthreads();
    for (int s = 128; s > 0; s >>= 1) {
        if (tid < s) red[tid] = fmaxf(red[tid], red[tid + s]);
        __syncthreads();
    }
    float qmax = red[0];
    __syncthreads();
    red[tid] = lmin;
    __syncthreads();
    for (int s = 128; s > 0; s >>= 1) {
        if (tid < s) red[tid] = fminf(red[tid], red[tid + s]);
        __syncthreads();
    }
    float qmin = red[0];
    __syncthreads();
    int nl = tid & 15, chunk = tid >> 4;             // 16 rows/block, 16 k-chunks of 256
    int n = blockIdx.x * 16 + nl;
    float pv = g_p[h * NN + n];
    float se = pv * (pv >= 0.f ? qmax : qmin);
    float M = fmaxf(se, 0.3f * se);
    float z = 0.f;
    int base = chunk * 256;
    for (int i = 0; i < 64; ++i) {
        f32x4 qv = *(const f32x4*)&qsh[base + i * 4];
#pragma unroll
        for (int k = 0; k < 4; ++k) {
            float s = pv * qv[k];
            s = fmaxf(s, 0.3f * s);
            z += __expf(s - M);
        }
    }
    red[chunk * 16 + nl] = z;
    __syncthreads();
    if (chunk == 0) {
        float Z = 0.f;
#pragma unroll
        for (int t = 0; t < 16; ++t) Z += red[t * 16 + nl];
        g_M[h * NN + n] = M;
        g_sc[h * NN + n] = 0.25f / Z;
    }
}

// ---------------- GEMM3 v8: R7 skeleton (128n x 512f, 512 thr, 1x exp) + BK=64 via
//                  dual 32-KB B buffers (glds-compatible 64-B rows) -> 32 barrier intervals.
//                  oacc[h*2+ks][n][f] = sum_{m in ks-slice} w_h[n][m]*featsH[h][f][m] ----------------
#define ALD 68   // A-tile padded row stride (f16): 136 B -> ~2-way banks on read & write
__global__ __launch_bounds__(512, 2) void k_gemm_out() {
    __shared__ f16 As[128 * ALD];       // 17 KB  [n][k0..63]
    __shared__ f16 BsL[512 * 32];       // 32 KB  [f][k0..31]
    __shared__ f16 BsH[512 * 32];       // 32 KB  [f][k32..63]
    int tid = threadIdx.x;
    int lane = tid & 63, wave = tid >> 6;        // 8 waves
    int wr = wave & 1;                           // n half (0..1)
    int wf = wave >> 1;                          // f quarter (0..3)
    int c = lane & 15, g = lane >> 4;
    int n0 = blockIdx.x * 128;
    int h = blockIdx.y;
    int ks = blockIdx.z;                         // k-slice: m in [ks*2048, +2048)
    int wn = tid >> 2, kq = (tid & 3) * 16;      // weight-gen: row wn (0..127), 16 k's
    float pv = g_p[h * NN + n0 + wn];
    float mv = g_M[h * NN + n0 + wn];
    float sv = g_sc[h * NN + n0 + wn];
    const float* qh = g_q + h * NN + ks * 2048;
    const f16* Bgl = g_featsH + (size_t)h * FF * NN + (size_t)ks * 2048;
    int brow = lane >> 2;                        // glds: lane's row within a 16-row group
    int bkof = (lane & 3) * 8;                   //       lane's k offset (f16 elems)
    f32x4 acc[4][8] = {};
    for (int kk = 0; kk < 2048; kk += 64) {
        // this iter's 16 attention weights, generated in registers (pre-barrier)
        f16x8 w0, w1;
#pragma unroll
        for (int half = 0; half < 2; ++half) {
            f32x4 qa = *(const f32x4*)(qh + kk + kq + half * 8);
            f32x4 qb = *(const f32x4*)(qh + kk + kq + half * 8 + 4);
#pragma unroll
            for (int k = 0; k < 4; ++k) {
                float s = pv * qa[k];
                s = fmaxf(s, 0.3f * s);
                if (half == 0) w0[k] = (f16)(__expf(s - mv) * sv);
                else           w1[k] = (f16)(__expf(s - mv) * sv);
            }
#pragma unroll
            for (int k = 0; k < 4; ++k) {
                float s = pv * qb[k];
                s = fmaxf(s, 0.3f * s);
                if (half == 0) w0[4 + k] = (f16)(__expf(s - mv) * sv);
                else           w1[4 + k] = (f16)(__expf(s - mv) * sv);
            }
        }
        __syncthreads();   // previous interval's LDS readers done
        *(f16x8*)&As[wn * ALD + kq] = w0;
        *(f16x8*)&As[wn * ALD + kq + 8] = w1;
        // B: wave stages its own 64 f-rows for BOTH k-halves: 4+4 glds16 of 16 rows each
#pragma unroll
        for (int j = 0; j < 4; ++j) {
            int frow = wave * 64 + j * 16;
            glds16(Bgl + (size_t)(frow + brow) * NN + kk + bkof,      &BsL[frow * 32]);
            glds16(Bgl + (size_t)(frow + brow) * NN + kk + 32 + bkof, &BsH[frow * 32]);
        }
        __syncthreads();   // drain -> tiles ready
#pragma unroll
        for (int s = 0; s < 2; ++s) {
            const f16* Bsrc = (s == 0) ? BsL : BsH;
            f16x8 af[4], bfr[8];
#pragma unroll
            for (int i = 0; i < 4; ++i)
                af[i] = *(const f16x8*)&As[(wr * 64 + i * 16 + c) * ALD + s * 32 + g * 8];
#pragma unroll
            for (int jj = 0; jj < 8; ++jj)
                bfr[jj] = *(const f16x8*)&Bsrc[(wf * 128 + jj * 16 + c) * 32 + g * 8];
#pragma unroll
            for (int i = 0; i < 4; ++i)
#pragma unroll
                for (int jj = 0; jj < 8; ++jj)
                    acc[i][jj] = __builtin_amdgcn_mfma_f32_16x16x32_f16(af[i], bfr[jj], acc[i][jj], 0, 0, 0);
        }
    }
    float* O = g_oacc + (size_t)(h * 2 + ks) * NN * FF;
#pragma unroll
    for (int jj = 0; jj < 8; ++jj) {
        int f = wf * 128 + jj * 16 + c;
#pragma unroll
        for (int i = 0; i < 4; ++i) {
            int r0 = n0 + wr * 64 + i * 16 + g * 4;
#pragma unroll
            for (int rr = 0; rr < 4; ++rr)
                O[(size_t)(r0 + rr) * FF + f] = acc[i][jj][rr];
        }
    }
}

// ---------------- final: out = relu(sum over 8 (h,ks) slabs) (fp32 out) ----------------
__global__ void k_reduce(float* __restrict__ out) {
    size_t i = ((size_t)blockIdx.x * 256 + threadIdx.x) * 4;   // 2048 blocks
    const size_t NF = (size_t)NN * FF;
    f32x4 s = *(const f32x4*)(g_oacc + i);
#pragma unroll
    for (int sl = 1; sl < 8; ++sl)
        s = s + *(const f32x4*)(g_oacc + sl * NF + i);
    f32x4 o;
#pragma unroll
    for (int rr = 0; rr < 4; ++rr) o[rr] = fmaxf(s[rr], 0.f);
    *(f32x4*)(out + i) = o;
}

extern "C" void kernel_launch(void* const* d_in, const int* in_sizes, int n_in,
                              void* d_out, int out_size, void* d_ws, size_t ws_size,
                              hipStream_t stream) {
    (void)in_sizes; (void)n_in; (void)out_size; (void)d_ws; (void)ws_size;
    const float* nodes  = (const float*)d_in[0];
    const float* edges  = (const float*)d_in[1];
    const float* labels = (const float*)d_in[2];
    const float* We     = (const float*)d_in[3];
    const float* be     = (const float*)d_in[4];
    const float* W      = (const float*)d_in[5];
    const float* b      = (const float*)d_in[6];
    const float* u      = (const float*)d_in[7];
    const float* v      = (const float*)d_in[8];

    k_prep<<<PREP_CONV + PREP_TRAN + PREP_UV, 256, 0, stream>>>(nodes, edges, labels, We, W, be, b, u, v);
    k_pq<<<4096, 256, 0, stream>>>();
    k_gemm_e<<<dim3(32, 8), 256, 0, stream>>>();
    k_gemm_feats<<<dim3(32, 8, 4), 256, 0, stream>>>();
    k_msz<<<dim3(256, 4), 256, 0, stream>>>();
    k_gemm_out<<<dim3(32, 4, 2), 512, 0, stream>>>();
    k_reduce<<<2048, 256, 0, stream>>>((float*)d_out);
}

// Round 12
// 266.448 us; speedup vs baseline: 1.4477x; 1.0489x over previous
//
#include <hip/hip_runtime.h>

#define NN 4096
#define DD 512
#define FF 512
#define HH 4

typedef _Float16 f16;
typedef f16 f16x8 __attribute__((ext_vector_type(8)));
typedef f16 f16x4 __attribute__((ext_vector_type(4)));
typedef float f32x4 __attribute__((ext_vector_type(4)));

// ---------------- async global->LDS (16 B per lane; LDS dest = uniform base + lane*16) ----------------
typedef __attribute__((address_space(1))) void gvoid;
typedef __attribute__((address_space(3))) void svoid;
__device__ __forceinline__ void glds16(const void* g, void* s) {
    __builtin_amdgcn_global_load_lds((gvoid*)g, (svoid*)s, 16, 0, 0);
}

// ---------------- static device workspace (fully rewritten every call) ----------------
__device__ __attribute__((aligned(16))) f16 g_nodesH[NN * DD];       //  4 MB
__device__ __attribute__((aligned(16))) f16 g_XH[NN * DD];           //  4 MB  edges+labels
__device__ __attribute__((aligned(16))) f16 g_WeTH[FF * DD];         //  0.5 MB  We^T[f][d]
__device__ __attribute__((aligned(16))) f16 g_WTH[HH * FF * DD];     //  2 MB  W^T[h][f][d]
__device__ __attribute__((aligned(16))) f16 g_eH[FF * NN];           //  4 MB  e^T[f][n]
__device__ __attribute__((aligned(16))) f16 g_featsH[HH * FF * NN];  // 16 MB  (feats+e)^T
__device__ __attribute__((aligned(16))) f16 g_oaccH[(size_t)2 * HH * NN * FF]; // 33.5 MB f16 partial slabs
__device__ float g_beF[FF];
__device__ float g_bF[HH * FF];
__device__ float g_tu[HH * DD], g_tv[HH * DD], g_bu[HH], g_bv[HH];
__device__ float g_p[HH * NN], g_q[HH * NN], g_M[HH * NN], g_sc[HH * NN];

#define PREP_CONV 16394
#define PREP_TRAN 320
#define PREP_UV   513

// ---------------- fused prep: fp32->f16 staging + weight transposes + u/v projections ----------------
__global__ __launch_bounds__(256) void k_prep(const float* __restrict__ nodes, const float* __restrict__ edges,
                                              const float* __restrict__ labels, const float* __restrict__ We,
                                              const float* __restrict__ W, const float* __restrict__ be,
                                              const float* __restrict__ b, const float* __restrict__ u,
                                              const float* __restrict__ v) {
    __shared__ float lds[64 * 65];
    int bx = blockIdx.x;
    int tid = threadIdx.x;
    if (bx < PREP_CONV) {
        int id = bx * 256 + tid;
        const int NDE = NN * DD;
        if (id < NDE) { g_nodesH[id] = (f16)nodes[id]; return; }
        id -= NDE;
        if (id < NDE) { g_XH[id] = (f16)(edges[id] + labels[id]); return; }
        id -= NDE;
        if (id < FF) { g_beF[id] = be[id]; return; }
        id -= FF;
        if (id < HH * FF) { g_bF[id] = b[id]; return; }
        return;
    }
    if (bx < PREP_CONV + PREP_TRAN) {
        int bid = bx - PREP_CONV;                    // 0..319
        int mi = bid >> 6;                           // 0 = We, 1..4 = W head
        int t64 = bid & 63;
        const float* src = (mi == 0) ? We : (W + (size_t)(mi - 1) * DD * FF);
        f16* dst = (mi == 0) ? g_WeTH : (g_WTH + (size_t)(mi - 1) * FF * DD);
        int ti = t64 >> 3, tj = t64 & 7;
        int r = tid >> 2, cseg = (tid & 3) * 16;
#pragma unroll
        for (int kq = 0; kq < 4; ++kq) {
            f32x4 vv = *(const f32x4*)(src + (size_t)(ti * 64 + r) * 512 + tj * 64 + cseg + kq * 4);
            *(f32x4*)&lds[r * 65 + cseg + kq * 4] = vv;
        }
        __syncthreads();
        int fl = tid >> 2, dseg = (tid & 3) * 16;
        f16x8 o0, o1;
#pragma unroll
        for (int k = 0; k < 8; ++k) o0[k] = (f16)lds[(dseg + k) * 65 + fl];
#pragma unroll
        for (int k = 0; k < 8; ++k) o1[k] = (f16)lds[(dseg + 8 + k) * 65 + fl];
        size_t ob = (size_t)(tj * 64 + fl) * 512 + ti * 64 + dseg;
        *(f16x8*)&dst[ob] = o0;
        *(f16x8*)&dst[ob + 8] = o1;
        return;
    }
    {
        int row = (bx - PREP_CONV - PREP_TRAN) * 4 + (tid >> 6);   // 2052 rows
        int lane = tid & 63;
        float su = 0.f, sv = 0.f;
        if (row < HH * DD) {
            int h = row >> 9, d = row & 511;
            size_t wb = (size_t)h * DD * FF + (size_t)d * FF;
#pragma unroll
            for (int j = 0; j < 8; ++j) {
                int f = lane + 64 * j;
                float wv = W[wb + f];
                su += wv * u[(size_t)h * FF + f];
                sv += wv * v[(size_t)h * FF + f];
            }
        } else if (row < HH * DD + HH) {
            int h = row - HH * DD;
#pragma unroll
            for (int j = 0; j < 8; ++j) {
                int f = lane + 64 * j;
                float bvv = b[(size_t)h * FF + f];
                su += bvv * u[(size_t)h * FF + f];
                sv += bvv * v[(size_t)h * FF + f];
            }
        }
#pragma unroll
        for (int m = 1; m < 64; m <<= 1) {
            su += __shfl_xor(su, m, 64);
            sv += __shfl_xor(sv, m, 64);
        }
        if (lane == 0 && row < HH * DD + HH) {
            if (row < HH * DD) { g_tu[row] = su; g_tv[row] = sv; }
            else { g_bu[row - HH * DD] = su; g_bv[row - HH * DD] = sv; }
        }
    }
}

// ---------------- p[h][n] = nodes[n].t_u[h] + bu[h];  q likewise (exact fp32 score path) ----------------
__global__ __launch_bounds__(256) void k_pq() {
    int row = blockIdx.x * 4 + (threadIdx.x >> 6);    // 4096 blocks -> 16384 rows = H*N
    int lane = threadIdx.x & 63;
    int h = row >> 12, n = row & 4095;
    const f16* nb = g_nodesH + (size_t)n * DD;
    const float* tu = g_tu + h * DD;
    const float* tv = g_tv + h * DD;
    float pa = 0.f, qa = 0.f;
#pragma unroll
    for (int j = 0; j < 8; ++j) {
        int d = lane + 64 * j;
        float nv = (float)nb[d];
        pa += nv * tu[d];
        qa += nv * tv[d];
    }
#pragma unroll
    for (int m = 1; m < 64; m <<= 1) {
        pa += __shfl_xor(pa, m, 64);
        qa += __shfl_xor(qa, m, 64);
    }
    if (lane == 0) {
        g_p[row] = pa + g_bu[h];
        g_q[row] = qa + g_bv[h];
    }
}

// ---------------- GEMM1 v2 (glds, BK=64, XOR-swizzled): eH[f][n] = f16((X @ We)[n][f] + be[f])
//                  tile 128n x 128f, grid (32,4) ----------------
__global__ __launch_bounds__(256, 2) void k_gemm_e() {
    __shared__ f16 As[128 * 64];        // 16 KB  [n][k], 128-B rows, chunks XOR-swizzled
    __shared__ f16 Bs[128 * 64];        // 16 KB  [f][k]
    int tid = threadIdx.x;
    int lane = tid & 63, wave = tid >> 6;        // 4 waves
    int wr = wave & 1, wf = wave >> 1;
    int c = lane & 15, g = lane >> 4;
    int n0 = blockIdx.x * 128, f0 = blockIdx.y * 128;
    int r8 = lane >> 3;                  // row within 8-row glds group
    int ksw = ((lane & 7) ^ r8) * 8;     // swizzled source k-chunk offset
    f32x4 acc[4][4] = {};
    for (int kk = 0; kk < DD; kk += 64) {
        __syncthreads();
#pragma unroll
        for (int j = 0; j < 4; ++j) {
            int row = wave * 32 + j * 8;
            glds16(g_XH   + (size_t)(n0 + row + r8) * DD + kk + ksw, &As[row * 64]);
            glds16(g_WeTH + (size_t)(f0 + row + r8) * DD + kk + ksw, &Bs[row * 64]);
        }
        __syncthreads();
#pragma unroll
        for (int s = 0; s < 2; ++s) {
            f16x8 af[4], bf[4];
#pragma unroll
            for (int i = 0; i < 4; ++i)
                af[i] = *(const f16x8*)&As[(wr * 64 + i * 16 + c) * 64 + (((s * 4 + g) ^ (c & 7)) * 8)];
#pragma unroll
            for (int jj = 0; jj < 4; ++jj)
                bf[jj] = *(const f16x8*)&Bs[(wf * 64 + jj * 16 + c) * 64 + (((s * 4 + g) ^ (c & 7)) * 8)];
#pragma unroll
            for (int i = 0; i < 4; ++i)
#pragma unroll
                for (int jj = 0; jj < 4; ++jj)
                    acc[i][jj] = __builtin_amdgcn_mfma_f32_16x16x32_f16(af[i], bf[jj], acc[i][jj], 0, 0, 0);
        }
    }
#pragma unroll
    for (int jj = 0; jj < 4; ++jj) {
        int f = f0 + wf * 64 + jj * 16 + c;
        float bv = g_beF[f];
#pragma unroll
        for (int i = 0; i < 4; ++i) {
            int r0 = n0 + wr * 64 + i * 16 + g * 4;
            f16x4 ov;
#pragma unroll
            for (int rr = 0; rr < 4; ++rr) ov[rr] = (f16)(acc[i][jj][rr] + bv);
            *(f16x4*)(g_eH + (size_t)f * NN + r0) = ov;
        }
    }
}

// ---------------- GEMM2 v2 (same structure): featsH[h][f][n] = f16((nodes@W_h)[n][f] + b + e)
//                  tile 128n x 128f, grid (32,4,4) = 512 blocks, 2/CU ----------------
__global__ __launch_bounds__(256, 2) void k_gemm_feats() {
    __shared__ f16 As[128 * 64];
    __shared__ f16 Bs[128 * 64];
    int tid = threadIdx.x;
    int lane = tid & 63, wave = tid >> 6;
    int wr = wave & 1, wf = wave >> 1;
    int c = lane & 15, g = lane >> 4;
    int n0 = blockIdx.x * 128, f0 = blockIdx.y * 128;
    int h = blockIdx.z;
    const f16* Bgl = g_WTH + (size_t)h * DD * FF;
    int r8 = lane >> 3;
    int ksw = ((lane & 7) ^ r8) * 8;
    f32x4 acc[4][4] = {};
    for (int kk = 0; kk < DD; kk += 64) {
        __syncthreads();
#pragma unroll
        for (int j = 0; j < 4; ++j) {
            int row = wave * 32 + j * 8;
            glds16(g_nodesH + (size_t)(n0 + row + r8) * DD + kk + ksw, &As[row * 64]);
            glds16(Bgl      + (size_t)(f0 + row + r8) * DD + kk + ksw, &Bs[row * 64]);
        }
        __syncthreads();
#pragma unroll
        for (int s = 0; s < 2; ++s) {
            f16x8 af[4], bf[4];
#pragma unroll
            for (int i = 0; i < 4; ++i)
                af[i] = *(const f16x8*)&As[(wr * 64 + i * 16 + c) * 64 + (((s * 4 + g) ^ (c & 7)) * 8)];
#pragma unroll
            for (int jj = 0; jj < 4; ++jj)
                bf[jj] = *(const f16x8*)&Bs[(wf * 64 + jj * 16 + c) * 64 + (((s * 4 + g) ^ (c & 7)) * 8)];
#pragma unroll
            for (int i = 0; i < 4; ++i)
#pragma unroll
                for (int jj = 0; jj < 4; ++jj)
                    acc[i][jj] = __builtin_amdgcn_mfma_f32_16x16x32_f16(af[i], bf[jj], acc[i][jj], 0, 0, 0);
        }
    }
#pragma unroll
    for (int jj = 0; jj < 4; ++jj) {
        int f = f0 + wf * 64 + jj * 16 + c;
        float bv = g_bF[h * FF + f];
#pragma unroll
        for (int i = 0; i < 4; ++i) {
            int r0 = n0 + wr * 64 + i * 16 + g * 4;
            f16x4 e4 = *(const f16x4*)(g_eH + (size_t)f * NN + r0);
            f16x4 ov;
#pragma unroll
            for (int rr = 0; rr < 4; ++rr)
                ov[rr] = (f16)(acc[i][jj][rr] + bv + (float)e4[rr]);
            *(f16x4*)(g_featsH + ((size_t)h * FF + f) * NN + r0) = ov;
        }
    }
}

// ---------------- softmax stats: closed-form M (lrelu monotone), single Z pass ----------------
__global__ __launch_bounds__(256) void k_msz() {
    __shared__ float qsh[NN];
    __shared__ float red[256];
    int h = blockIdx.y;
    int tid = threadIdx.x;
    float lmax = -1e30f, lmin = 1e30f;
    for (int i = tid; i < NN; i += 256) {
        float qv = g_q[h * NN + i];
        qsh[i] = qv;
        lmax = fmaxf(lmax, qv);
        lmin = fminf(lmin, qv);
    }
    red[tid] = lmax;
    __syncthreads();
    for (int s = 128; s > 0; s >>= 1) {
        if (tid < s) red[tid] = fmaxf(red[tid], red[tid + s]);
        __syncthreads();
    }
    float qmax = red[0];
    __syncthreads();
    red[tid] = lmin;
    __syncthreads();
    for (int s = 128; s > 0; s >>= 1) {
        if (tid < s) red[tid] = fminf(red[tid], red[tid + s]);
        __syncthreads();
    }
    float qmin = red[0];
    __syncthreads();
    int nl = tid & 15, chunk = tid >> 4;             // 16 rows/block, 16 k-chunks of 256
    int n = blockIdx.x * 16 + nl;
    float pv = g_p[h * NN + n];
    float se = pv * (pv >= 0.f ? qmax : qmin);
    float M = fmaxf(se, 0.3f * se);
    float z = 0.f;
    int base = chunk * 256;
    for (int i = 0; i < 64; ++i) {
        f32x4 qv = *(const f32x4*)&qsh[base + i * 4];
#pragma unroll
        for (int k = 0; k < 4; ++k) {
            float s = pv * qv[k];
            s = fmaxf(s, 0.3f * s);
            z += __expf(s - M);
        }
    }
    red[chunk * 16 + nl] = z;
    __syncthreads();
    if (chunk == 0) {
        float Z = 0.f;
#pragma unroll
        for (int t = 0; t < 16; ++t) Z += red[t * 16 + nl];
        g_M[h * NN + n] = M;
        g_sc[h * NN + n] = 0.25f / Z;
    }
}

// ---------------- GEMM3 v9: 128n x 512f, 512 thr, BK=64 dual B buffers, 1x exp,
//                  B k-chunks XOR-swizzled (8-way -> 4-way banks), f16 output slabs ----------------
#define ALD 68   // A-tile padded row stride (f16)
__global__ __launch_bounds__(512, 2) void k_gemm_out() {
    __shared__ f16 As[128 * ALD];       // 17 KB  [n][k0..63]
    __shared__ f16 BsL[512 * 32];       // 32 KB  [f][k0..31]
    __shared__ f16 BsH[512 * 32];       // 32 KB  [f][k32..63]
    int tid = threadIdx.x;
    int lane = tid & 63, wave = tid >> 6;        // 8 waves
    int wr = wave & 1;                           // n half (0..1)
    int wf = wave >> 1;                          // f quarter (0..3)
    int c = lane & 15, g = lane >> 4;
    int n0 = blockIdx.x * 128;
    int h = blockIdx.y;
    int ks = blockIdx.z;                         // k-slice: m in [ks*2048, +2048)
    int wn = tid >> 2, kq = (tid & 3) * 16;      // weight-gen: row wn (0..127), 16 k's
    float pv = g_p[h * NN + n0 + wn];
    float mv = g_M[h * NN + n0 + wn];
    float sv = g_sc[h * NN + n0 + wn];
    const float* qh = g_q + h * NN + ks * 2048;
    const f16* Bgl = g_featsH + (size_t)h * FF * NN + (size_t)ks * 2048;
    int brow = lane >> 2;                        // glds: lane's row within a 16-row group
    int bksw = ((lane & 3) ^ (brow & 3)) * 8;    //       swizzled source k-chunk offset
    f32x4 acc[4][8] = {};
    for (int kk = 0; kk < 2048; kk += 64) {
        // this iter's 16 attention weights, generated in registers (pre-barrier)
        f16x8 w0, w1;
#pragma unroll
        for (int half = 0; half < 2; ++half) {
            f32x4 qa = *(const f32x4*)(qh + kk + kq + half * 8);
            f32x4 qb = *(const f32x4*)(qh + kk + kq + half * 8 + 4);
#pragma unroll
            for (int k = 0; k < 4; ++k) {
                float s = pv * qa[k];
                s = fmaxf(s, 0.3f * s);
                if (half == 0) w0[k] = (f16)(__expf(s - mv) * sv);
                else           w1[k] = (f16)(__expf(s - mv) * sv);
            }
#pragma unroll
            for (int k = 0; k < 4; ++k) {
                float s = pv * qb[k];
                s = fmaxf(s, 0.3f * s);
                if (half == 0) w0[4 + k] = (f16)(__expf(s - mv) * sv);
                else           w1[4 + k] = (f16)(__expf(s - mv) * sv);
            }
        }
        __syncthreads();   // previous interval's LDS readers done
        *(f16x8*)&As[wn * ALD + kq] = w0;
        *(f16x8*)&As[wn * ALD + kq + 8] = w1;
        // B: wave stages its own 64 f-rows for BOTH k-halves: 4+4 glds16 of 16 rows each
#pragma unroll
        for (int j = 0; j < 4; ++j) {
            int frow = wave * 64 + j * 16;
            glds16(Bgl + (size_t)(frow + brow) * NN + kk + bksw,      &BsL[frow * 32]);
            glds16(Bgl + (size_t)(frow + brow) * NN + kk + 32 + bksw, &BsH[frow * 32]);
        }
        __syncthreads();   // drain -> tiles ready
#pragma unroll
        for (int s = 0; s < 2; ++s) {
            const f16* Bsrc = (s == 0) ? BsL : BsH;
            f16x8 af[4], bfr[8];
#pragma unroll
            for (int i = 0; i < 4; ++i)
                af[i] = *(const f16x8*)&As[(wr * 64 + i * 16 + c) * ALD + s * 32 + g * 8];
#pragma unroll
            for (int jj = 0; jj < 8; ++jj)
                bfr[jj] = *(const f16x8*)&Bsrc[(wf * 128 + jj * 16 + c) * 32 + ((g ^ (c & 3)) * 8)];
#pragma unroll
            for (int i = 0; i < 4; ++i)
#pragma unroll
                for (int jj = 0; jj < 8; ++jj)
                    acc[i][jj] = __builtin_amdgcn_mfma_f32_16x16x32_f16(af[i], bfr[jj], acc[i][jj], 0, 0, 0);
        }
    }
    f16* O = g_oaccH + (size_t)(h * 2 + ks) * NN * FF;
#pragma unroll
    for (int jj = 0; jj < 8; ++jj) {
        int f = wf * 128 + jj * 16 + c;
#pragma unroll
        for (int i = 0; i < 4; ++i) {
            int r0 = n0 + wr * 64 + i * 16 + g * 4;
#pragma unroll
            for (int rr = 0; rr < 4; ++rr)
                O[(size_t)(r0 + rr) * FF + f] = (f16)acc[i][jj][rr];
        }
    }
}

// ---------------- final: out = relu(sum over 8 f16 slabs) (fp32 out) ----------------
__global__ void k_reduce(float* __restrict__ out) {
    size_t i = ((size_t)blockIdx.x * 256 + threadIdx.x) * 4;   // 2048 blocks
    const size_t NF = (size_t)NN * FF;
    f32x4 s = {0.f, 0.f, 0.f, 0.f};
#pragma unroll
    for (int sl = 0; sl < 8; ++sl) {
        f16x4 v = *(const f16x4*)(g_oaccH + sl * NF + i);
#pragma unroll
        for (int rr = 0; rr < 4; ++rr) s[rr] += (float)v[rr];
    }
    f32x4 o;
#pragma unroll
    for (int rr = 0; rr < 4; ++rr) o[rr] = fmaxf(s[rr], 0.f);
    *(f32x4*)(out + i) = o;
}

extern "C" void kernel_launch(void* const* d_in, const int* in_sizes, int n_in,
                              void* d_out, int out_size, void* d_ws, size_t ws_size,
                              hipStream_t stream) {
    (void)in_sizes; (void)n_in; (void)out_size; (void)d_ws; (void)ws_size;
    const float* nodes  = (const float*)d_in[0];
    const float* edges  = (const float*)d_in[1];
    const float* labels = (const float*)d_in[2];
    const float* We     = (const float*)d_in[3];
    const float* be     = (const float*)d_in[4];
    const float* W      = (const float*)d_in[5];
    const float* b      = (const float*)d_in[6];
    const float* u      = (const float*)d_in[7];
    const float* v      = (const float*)d_in[8];

    k_prep<<<PREP_CONV + PREP_TRAN + PREP_UV, 256, 0, stream>>>(nodes, edges, labels, We, W, be, b, u, v);
    k_pq<<<4096, 256, 0, stream>>>();
    k_gemm_e<<<dim3(32, 4), 256, 0, stream>>>();
    k_gemm_feats<<<dim3(32, 4, 4), 256, 0, stream>>>();
    k_msz<<<dim3(256, 4), 256, 0, stream>>>();
    k_gemm_out<<<dim3(32, 4, 2), 512, 0, stream>>>();
    k_reduce<<<2048, 256, 0, stream>>>((float*)d_out);
}

// Round 13
// 260.371 us; speedup vs baseline: 1.4815x; 1.0233x over previous
//
#include <hip/hip_runtime.h>

#define NN 4096
#define DD 512
#define FF 512
#define HH 4
#define KK 1024   // concat GEMM depth

typedef _Float16 f16;
typedef f16 f16x8 __attribute__((ext_vector_type(8)));
typedef f16 f16x4 __attribute__((ext_vector_type(4)));
typedef float f32x4 __attribute__((ext_vector_type(4)));

// ---------------- async global->LDS (16 B per lane; LDS dest = uniform base + lane*16) ----------------
typedef __attribute__((address_space(1))) void gvoid;
typedef __attribute__((address_space(3))) void svoid;
__device__ __forceinline__ void glds16(const void* g, void* s) {
    __builtin_amdgcn_global_load_lds((gvoid*)g, (svoid*)s, 16, 0, 0);
}

// ---------------- static device workspace (fully rewritten every call) ----------------
__device__ __attribute__((aligned(16))) f16 g_catA[NN * KK];         //  8 MB  [n][ nodes(512) | X(512) ]
__device__ __attribute__((aligned(16))) f16 g_catB[HH * FF * KK];    //  4 MB  [h][f][ W_h^T(512) | We^T(512) ]
__device__ __attribute__((aligned(16))) f16 g_featsH[HH * FF * NN];  // 16 MB  (feats+e)^T
__device__ __attribute__((aligned(16))) f16 g_oaccH[(size_t)2 * HH * NN * FF]; // 33.5 MB f16 partial slabs
__device__ float g_bcat[HH * FF];                                    // b_h[f] + be[f]
__device__ float g_tu[HH * DD], g_tv[HH * DD], g_bu[HH], g_bv[HH];
__device__ float g_p[HH * NN], g_q[HH * NN], g_M[HH * NN], g_sc[HH * NN];

#define PREP_CONV 16392   // 2*NN*DD + HH*FF ids
#define PREP_TRAN 320
#define PREP_UV   513

// ---------------- fused prep: fp32->f16 concat staging + weight transposes + u/v projections ----------------
__global__ __launch_bounds__(256) void k_prep(const float* __restrict__ nodes, const float* __restrict__ edges,
                                              const float* __restrict__ labels, const float* __restrict__ We,
                                              const float* __restrict__ W, const float* __restrict__ be,
                                              const float* __restrict__ b, const float* __restrict__ u,
                                              const float* __restrict__ v) {
    __shared__ float lds[64 * 65];
    int bx = blockIdx.x;
    int tid = threadIdx.x;
    if (bx < PREP_CONV) {
        int id = bx * 256 + tid;
        const int NDE = NN * DD;
        if (id < NDE) {                      // nodes -> catA[:, 0:512]
            g_catA[(size_t)(id >> 9) * KK + (id & 511)] = (f16)nodes[id];
            return;
        }
        id -= NDE;
        if (id < NDE) {                      // edges+labels -> catA[:, 512:1024]
            g_catA[(size_t)(id >> 9) * KK + 512 + (id & 511)] = (f16)(edges[id] + labels[id]);
            return;
        }
        id -= NDE;
        if (id < HH * FF) { g_bcat[id] = b[id] + be[id & 511]; return; }
        return;
    }
    if (bx < PREP_CONV + PREP_TRAN) {
        int bid = bx - PREP_CONV;                    // 0..319
        int mi = bid >> 6;                           // 0 = We, 1..4 = W head
        int t64 = bid & 63;
        const float* src = (mi == 0) ? We : (W + (size_t)(mi - 1) * DD * FF);
        int ti = t64 >> 3, tj = t64 & 7;             // 64x64 tile coords in [d][f]
        int r = tid >> 2, cseg = (tid & 3) * 16;
#pragma unroll
        for (int kq = 0; kq < 4; ++kq) {
            f32x4 vv = *(const f32x4*)(src + (size_t)(ti * 64 + r) * 512 + tj * 64 + cseg + kq * 4);
            *(f32x4*)&lds[r * 65 + cseg + kq * 4] = vv;
        }
        __syncthreads();
        int fl = tid >> 2, dseg = (tid & 3) * 16;
        f16x8 o0, o1;
#pragma unroll
        for (int k = 0; k < 8; ++k) o0[k] = (f16)lds[(dseg + k) * 65 + fl];
#pragma unroll
        for (int k = 0; k < 8; ++k) o1[k] = (f16)lds[(dseg + 8 + k) * 65 + fl];
        size_t frow = (size_t)(tj * 64 + fl);
        size_t dcol = (size_t)(ti * 64 + dseg);
        if (mi == 0) {                               // We^T -> every head's [512:1024] slice
#pragma unroll
            for (int hh = 0; hh < HH; ++hh) {
                size_t ob = ((size_t)hh * FF + frow) * KK + 512 + dcol;
                *(f16x8*)&g_catB[ob] = o0;
                *(f16x8*)&g_catB[ob + 8] = o1;
            }
        } else {                                     // W_h^T -> head's [0:512] slice
            size_t ob = ((size_t)(mi - 1) * FF + frow) * KK + dcol;
            *(f16x8*)&g_catB[ob] = o0;
            *(f16x8*)&g_catB[ob + 8] = o1;
        }
        return;
    }
    {
        int row = (bx - PREP_CONV - PREP_TRAN) * 4 + (tid >> 6);   // 2052 rows
        int lane = tid & 63;
        float su = 0.f, sv = 0.f;
        if (row < HH * DD) {
            int h = row >> 9, d = row & 511;
            size_t wb = (size_t)h * DD * FF + (size_t)d * FF;
#pragma unroll
            for (int j = 0; j < 8; ++j) {
                int f = lane + 64 * j;
                float wv = W[wb + f];
                su += wv * u[(size_t)h * FF + f];
                sv += wv * v[(size_t)h * FF + f];
            }
        } else if (row < HH * DD + HH) {
            int h = row - HH * DD;
#pragma unroll
            for (int j = 0; j < 8; ++j) {
                int f = lane + 64 * j;
                float bvv = b[(size_t)h * FF + f];
                su += bvv * u[(size_t)h * FF + f];
                sv += bvv * v[(size_t)h * FF + f];
            }
        }
#pragma unroll
        for (int m = 1; m < 64; m <<= 1) {
            su += __shfl_xor(su, m, 64);
            sv += __shfl_xor(sv, m, 64);
        }
        if (lane == 0 && row < HH * DD + HH) {
            if (row < HH * DD) { g_tu[row] = su; g_tv[row] = sv; }
            else { g_bu[row - HH * DD] = su; g_bv[row - HH * DD] = sv; }
        }
    }
}

// ---------------- p[h][n] = nodes[n].t_u[h] + bu[h];  q likewise (exact fp32 score path) ----------------
__global__ __launch_bounds__(256) void k_pq() {
    int row = blockIdx.x * 4 + (threadIdx.x >> 6);    // 4096 blocks -> 16384 rows = H*N
    int lane = threadIdx.x & 63;
    int h = row >> 12, n = row & 4095;
    const f16* nb = g_catA + (size_t)n * KK;          // nodes slice [0:512]
    const float* tu = g_tu + h * DD;
    const float* tv = g_tv + h * DD;
    float pa = 0.f, qa = 0.f;
#pragma unroll
    for (int j = 0; j < 8; ++j) {
        int d = lane + 64 * j;
        float nv = (float)nb[d];
        pa += nv * tu[d];
        qa += nv * tv[d];
    }
#pragma unroll
    for (int m = 1; m < 64; m <<= 1) {
        pa += __shfl_xor(pa, m, 64);
        qa += __shfl_xor(qa, m, 64);
    }
    if (lane == 0) {
        g_p[row] = pa + g_bu[h];
        g_q[row] = qa + g_bv[h];
    }
}

// ---------------- concat GEMM: featsH[h][f][n] = f16(([nodes|X] @ [W_h;We])[n][f] + bcat)
//                  K=1024, BK=64, tile 128n x 128f, glds + XOR-swizzle ----------------
__global__ __launch_bounds__(256, 2) void k_gemm_feats() {
    __shared__ f16 As[128 * 64];        // 16 KB  [n][k], 128-B rows, chunks XOR-swizzled
    __shared__ f16 Bs[128 * 64];        // 16 KB  [f][k]
    int tid = threadIdx.x;
    int lane = tid & 63, wave = tid >> 6;        // 4 waves
    int wr = wave & 1, wf = wave >> 1;
    int c = lane & 15, g = lane >> 4;
    int n0 = blockIdx.x * 128, f0 = blockIdx.y * 128;
    int h = blockIdx.z;
    const f16* Bgl = g_catB + (size_t)h * FF * KK;
    int r8 = lane >> 3;                  // row within 8-row glds group
    int ksw = ((lane & 7) ^ r8) * 8;     // swizzled source k-chunk offset
    f32x4 acc[4][4] = {};
    for (int kk = 0; kk < KK; kk += 64) {
        __syncthreads();
#pragma unroll
        for (int j = 0; j < 4; ++j) {
            int row = wave * 32 + j * 8;
            glds16(g_catA + (size_t)(n0 + row + r8) * KK + kk + ksw, &As[row * 64]);
            glds16(Bgl    + (size_t)(f0 + row + r8) * KK + kk + ksw, &Bs[row * 64]);
        }
        __syncthreads();
#pragma unroll
        for (int s = 0; s < 2; ++s) {
            f16x8 af[4], bf[4];
#pragma unroll
            for (int i = 0; i < 4; ++i)
                af[i] = *(const f16x8*)&As[(wr * 64 + i * 16 + c) * 64 + (((s * 4 + g) ^ (c & 7)) * 8)];
#pragma unroll
            for (int jj = 0; jj < 4; ++jj)
                bf[jj] = *(const f16x8*)&Bs[(wf * 64 + jj * 16 + c) * 64 + (((s * 4 + g) ^ (c & 7)) * 8)];
#pragma unroll
            for (int i = 0; i < 4; ++i)
#pragma unroll
                for (int jj = 0; jj < 4; ++jj)
                    acc[i][jj] = __builtin_amdgcn_mfma_f32_16x16x32_f16(af[i], bf[jj], acc[i][jj], 0, 0, 0);
        }
    }
#pragma unroll
    for (int jj = 0; jj < 4; ++jj) {
        int f = f0 + wf * 64 + jj * 16 + c;
        float bv = g_bcat[h * FF + f];
#pragma unroll
        for (int i = 0; i < 4; ++i) {
            int r0 = n0 + wr * 64 + i * 16 + g * 4;
            f16x4 ov;
#pragma unroll
            for (int rr = 0; rr < 4; ++rr) ov[rr] = (f16)(acc[i][jj][rr] + bv);
            *(f16x4*)(g_featsH + ((size_t)h * FF + f) * NN + r0) = ov;
        }
    }
}

// ---------------- softmax stats: closed-form M (lrelu monotone), single Z pass ----------------
__global__ __launch_bounds__(256) void k_msz() {
    __shared__ float qsh[NN];
    __shared__ float red[256];
    int h = blockIdx.y;
    int tid = threadIdx.x;
    float lmax = -1e30f, lmin = 1e30f;
    for (int i = tid; i < NN; i += 256) {
        float qv = g_q[h * NN + i];
        qsh[i] = qv;
        lmax = fmaxf(lmax, qv);
        lmin = fminf(lmin, qv);
    }
    red[tid] = lmax;
    __syncthreads();
    for (int s = 128; s > 0; s >>= 1) {
        if (tid < s) red[tid] = fmaxf(red[tid], red[tid + s]);
        __syncthreads();
    }
    float qmax = red[0];
    __syncthreads();
    red[tid] = lmin;
    __syncthreads();
    for (int s = 128; s > 0; s >>= 1) {
        if (tid < s) red[tid] = fminf(red[tid], red[tid + s]);
        __syncthreads();
    }
    float qmin = red[0];
    __syncthreads();
    int nl = tid & 15, chunk = tid >> 4;             // 16 rows/block, 16 k-chunks of 256
    int n = blockIdx.x * 16 + nl;
    float pv = g_p[h * NN + n];
    float se = pv * (pv >= 0.f ? qmax : qmin);
    float M = fmaxf(se, 0.3f * se);
    float z = 0.f;
    int base = chunk * 256;
    for (int i = 0; i < 64; ++i) {
        f32x4 qv = *(const f32x4*)&qsh[base + i * 4];
#pragma unroll
        for (int k = 0; k < 4; ++k) {
            float s = pv * qv[k];
            s = fmaxf(s, 0.3f * s);
            z += __expf(s - M);
        }
    }
    red[chunk * 16 + nl] = z;
    __syncthreads();
    if (chunk == 0) {
        float Z = 0.f;
#pragma unroll
        for (int t = 0; t < 16; ++t) Z += red[t * 16 + nl];
        g_M[h * NN + n] = M;
        g_sc[h * NN + n] = 0.25f / Z;
    }
}

// ---------------- GEMM3 (unchanged from R12 best): 128n x 512f, 512 thr, BK=64 dual B buffers,
//                  1x exp, f16 output slabs ----------------
#define ALD 68   // A-tile padded row stride (f16)
__global__ __launch_bounds__(512, 2) void k_gemm_out() {
    __shared__ f16 As[128 * ALD];       // 17 KB  [n][k0..63]
    __shared__ f16 BsL[512 * 32];       // 32 KB  [f][k0..31]
    __shared__ f16 BsH[512 * 32];       // 32 KB  [f][k32..63]
    int tid = threadIdx.x;
    int lane = tid & 63, wave = tid >> 6;        // 8 waves
    int wr = wave & 1;                           // n half (0..1)
    int wf = wave >> 1;                          // f quarter (0..3)
    int c = lane & 15, g = lane >> 4;
    int n0 = blockIdx.x * 128;
    int h = blockIdx.y;
    int ks = blockIdx.z;                         // k-slice: m in [ks*2048, +2048)
    int wn = tid >> 2, kq = (tid & 3) * 16;      // weight-gen: row wn (0..127), 16 k's
    float pv = g_p[h * NN + n0 + wn];
    float mv = g_M[h * NN + n0 + wn];
    float sv = g_sc[h * NN + n0 + wn];
    const float* qh = g_q + h * NN + ks * 2048;
    const f16* Bgl = g_featsH + (size_t)h * FF * NN + (size_t)ks * 2048;
    int brow = lane >> 2;                        // glds: lane's row within a 16-row group
    int bksw = ((lane & 3) ^ (brow & 3)) * 8;    //       swizzled source k-chunk offset
    f32x4 acc[4][8] = {};
    for (int kk = 0; kk < 2048; kk += 64) {
        f16x8 w0, w1;
#pragma unroll
        for (int half = 0; half < 2; ++half) {
            f32x4 qa = *(const f32x4*)(qh + kk + kq + half * 8);
            f32x4 qb = *(const f32x4*)(qh + kk + kq + half * 8 + 4);
#pragma unroll
            for (int k = 0; k < 4; ++k) {
                float s = pv * qa[k];
                s = fmaxf(s, 0.3f * s);
                if (half == 0) w0[k] = (f16)(__expf(s - mv) * sv);
                else           w1[k] = (f16)(__expf(s - mv) * sv);
            }
#pragma unroll
            for (int k = 0; k < 4; ++k) {
                float s = pv * qb[k];
                s = fmaxf(s, 0.3f * s);
                if (half == 0) w0[4 + k] = (f16)(__expf(s - mv) * sv);
                else           w1[4 + k] = (f16)(__expf(s - mv) * sv);
            }
        }
        __syncthreads();   // previous interval's LDS readers done
        *(f16x8*)&As[wn * ALD + kq] = w0;
        *(f16x8*)&As[wn * ALD + kq + 8] = w1;
#pragma unroll
        for (int j = 0; j < 4; ++j) {
            int frow = wave * 64 + j * 16;
            glds16(Bgl + (size_t)(frow + brow) * NN + kk + bksw,      &BsL[frow * 32]);
            glds16(Bgl + (size_t)(frow + brow) * NN + kk + 32 + bksw, &BsH[frow * 32]);
        }
        __syncthreads();   // drain -> tiles ready
#pragma unroll
        for (int s = 0; s < 2; ++s) {
            const f16* Bsrc = (s == 0) ? BsL : BsH;
            f16x8 af[4], bfr[8];
#pragma unroll
            for (int i = 0; i < 4; ++i)
                af[i] = *(const f16x8*)&As[(wr * 64 + i * 16 + c) * ALD + s * 32 + g * 8];
#pragma unroll
            for (int jj = 0; jj < 8; ++jj)
                bfr[jj] = *(const f16x8*)&Bsrc[(wf * 128 + jj * 16 + c) * 32 + ((g ^ (c & 3)) * 8)];
#pragma unroll
            for (int i = 0; i < 4; ++i)
#pragma unroll
                for (int jj = 0; jj < 8; ++jj)
                    acc[i][jj] = __builtin_amdgcn_mfma_f32_16x16x32_f16(af[i], bfr[jj], acc[i][jj], 0, 0, 0);
        }
    }
    f16* O = g_oaccH + (size_t)(h * 2 + ks) * NN * FF;
#pragma unroll
    for (int jj = 0; jj < 8; ++jj) {
        int f = wf * 128 + jj * 16 + c;
#pragma unroll
        for (int i = 0; i < 4; ++i) {
            int r0 = n0 + wr * 64 + i * 16 + g * 4;
#pragma unroll
            for (int rr = 0; rr < 4; ++rr)
                O[(size_t)(r0 + rr) * FF + f] = (f16)acc[i][jj][rr];
        }
    }
}

// ---------------- final: out = relu(sum over 8 f16 slabs) (fp32 out) ----------------
__global__ void k_reduce(float* __restrict__ out) {
    size_t i = ((size_t)blockIdx.x * 256 + threadIdx.x) * 4;   // 2048 blocks
    const size_t NF = (size_t)NN * FF;
    f32x4 s = {0.f, 0.f, 0.f, 0.f};
#pragma unroll
    for (int sl = 0; sl < 8; ++sl) {
        f16x4 v = *(const f16x4*)(g_oaccH + sl * NF + i);
#pragma unroll
        for (int rr = 0; rr < 4; ++rr) s[rr] += (float)v[rr];
    }
    f32x4 o;
#pragma unroll
    for (int rr = 0; rr < 4; ++rr) o[rr] = fmaxf(s[rr], 0.f);
    *(f32x4*)(out + i) = o;
}

extern "C" void kernel_launch(void* const* d_in, const int* in_sizes, int n_in,
                              void* d_out, int out_size, void* d_ws, size_t ws_size,
                              hipStream_t stream) {
    (void)in_sizes; (void)n_in; (void)out_size; (void)d_ws; (void)ws_size;
    const float* nodes  = (const float*)d_in[0];
    const float* edges  = (const float*)d_in[1];
    const float* labels = (const float*)d_in[2];
    const float* We     = (const float*)d_in[3];
    const float* be     = (const float*)d_in[4];
    const float* W      = (const float*)d_in[5];
    const float* b      = (const float*)d_in[6];
    const float* u      = (const float*)d_in[7];
    const float* v      = (const float*)d_in[8];

    k_prep<<<PREP_CONV + PREP_TRAN + PREP_UV, 256, 0, stream>>>(nodes, edges, labels, We, W, be, b, u, v);
    k_pq<<<4096, 256, 0, stream>>>();
    k_gemm_feats<<<dim3(32, 4, 4), 256, 0, stream>>>();
    k_msz<<<dim3(256, 4), 256, 0, stream>>>();
    k_gemm_out<<<dim3(32, 4, 2), 512, 0, stream>>>();
    k_reduce<<<2048, 256, 0, stream>>>((float*)d_out);
}